// Round 12
// baseline (347.983 us; speedup 1.0000x reference)
//
#include <hip/hip_runtime.h>
#include <math.h>

// ---------------------------------------------------------------------------
// Sinkhorn ETP (FASTopic) on MI355X.
// n=256 topics, m=32768 words, D=384.
//
//   log_K0[i,j] = G[i,j] + su0[i] + sv0[j],  G = 40 * x@y^T
//   Per iteration:  W[j] = log_b - lse_i(G+su);  su'[i] = log_a - lse_j(G+W)
//   Final: transp[i,j] = exp(G+su[i]+W[j]); M = nx[i]+ny[j]-0.05*G;
//          loss = sum(transp*M)
//
// R16 (WIN 383->308): persistent iteration kernel (1.9us/iter proven), but
// separate gemm + 76us kernel-boundary G-load tax.
// R17 (spill) / R18 / R19 (allocator refused to materialize E; VGPR stuck
// at 196 -> silent remat = R18): fragment-layout iterations run ~4us/iter
// vs R16's 1.9 for reasons counters don't localize. Three rounds spent;
// abandon fragment-layout iteration.
//
// R20: fuse via IN-KERNEL own-L2 exchange. The R9-R15 tax is a KERNEL
// BOUNDARY property (drain/visibility of fresh dirty data); within one
// kernel a block writing its own 64KB of G and reading it back after
// __syncthreads hits its own XCD's dirty L2 (32 blocks x 64KB = 2MB << 4MB).
// Phase A: MFMA acc (proven R18 code) -> store acc to G in R16's tiled
// layout [b][i][c] (plain stores, L2-resident; acc dead after) -> barrier ->
// load tile[32] in R16's thread mapping (no co-residence -> no R17 spill) ->
// R16's iteration code VERBATIM (proven 1.9us/iter, 0 conflicts) ->
// Phase D: fused finalize from tile.
// Predicted: fused_k 135-160us (A ~30 + exch ~5 + 51x1.9 + D ~10), total
// 160-190us; conflicts -> ~0; FETCH ~27MB (G readback = L2 hits).
// Falsifiers: (a) fused ~210+, FETCH +17MB -> tax applies in-kernel too ->
// revert to R16 split; (b) WRITE >> 90MB -> spill returned.
// ---------------------------------------------------------------------------

#define N_TOPIC 256
#define N_WORD  32768

static constexpr float LOG_A = -5.545177444479562f;    // log(1/256 + 1e-30)
static constexpr float LOG_B = -10.397207708399179f;   // log(1/32768 + 1e-30)
static constexpr float BVAL  = 3.0517578125e-05f;      // 1/32768

typedef float f32x4 __attribute__((ext_vector_type(4)));
typedef short bf16x8 __attribute__((ext_vector_type(8)));

#define PIN4(v) asm volatile("" : "+v"((v).x), "+v"((v).y), "+v"((v).z), "+v"((v).w))

// ---------------------------------------------------------------- init ------
__global__ __launch_bounds__(256) void init_k(
    const float* __restrict__ x, const float* __restrict__ y,
    float* __restrict__ nx, float* __restrict__ ny, float* __restrict__ su,
    unsigned* __restrict__ colerr, int* __restrict__ active,
    int* __restrict__ counters, float* __restrict__ out)
{
    const int b = blockIdx.x, t = threadIdx.x;
    const int w = t >> 6, l = t & 63;
    if (b < 8192) {                       // ||y_j||^2, 4 rows/block (wave per row)
        const int r = (b << 2) + w;
        const float4* y4 = (const float4*)y;
        float4 v = y4[r * 96 + l];
        float s = v.x * v.x + v.y * v.y + v.z * v.z + v.w * v.w;
        if (l < 32) {
            float4 u = y4[r * 96 + 64 + l];
            s += u.x * u.x + u.y * u.y + u.z * u.z + u.w * u.w;
        }
        for (int off = 32; off; off >>= 1) s += __shfl_down(s, off);
        if (l == 0) ny[r] = s;
    } else if (b < 8256) {                // ||x_i||^2 and su0 = -20*nx
        const int r = ((b - 8192) << 2) + w;
        const float4* x4 = (const float4*)x;
        float4 v = x4[r * 96 + l];
        float s = v.x * v.x + v.y * v.y + v.z * v.z + v.w * v.w;
        if (l < 32) {
            float4 u = x4[r * 96 + 64 + l];
            s += u.x * u.x + u.y * u.y + u.z * u.z + u.w * u.w;
        }
        for (int off = 32; off; off >>= 1) s += __shfl_down(s, off);
        if (l == 0) { nx[r] = s; su[r] = -20.f * s; }
    } else {
        for (int k = t; k < 4096; k += 256) counters[k] = 0;
        if (t == 0) { colerr[0] = 0u; colerr[1] = 0u; active[0] = 1; out[0] = 0.f; }
    }
}

// Exact 3-way bf16 truncation split: v = b0 + b1 + b2 (+ r3, |r3|<=2^-27|v|).
static __device__ __forceinline__ void split3(float v, ushort& h0, ushort& h1, ushort& h2)
{
    unsigned u0 = __float_as_uint(v);
    h0 = (ushort)(u0 >> 16);
    float r1 = v - __uint_as_float(u0 & 0xFFFF0000u);
    unsigned u1 = __float_as_uint(r1);
    h1 = (ushort)(u1 >> 16);
    float r2 = r1 - __uint_as_float(u1 & 0xFFFF0000u);
    h2 = (ushort)(__float_as_uint(r2) >> 16);
}

// ----------------------------------------------- persistent barrier ---------
static __device__ __forceinline__ bool bar_arrive(int* cnt, int ph, int t, int* lastf)
{
    __threadfence();
    if (t == 0) *lastf = (atomicAdd(&cnt[ph], 1) == 255);
    __syncthreads();
    return *lastf != 0;
}
static __device__ __forceinline__ void bar_release(int* gen, int ph, int t)
{
    __threadfence();
    if (t == 0) atomicExch(gen, ph);
}
static __device__ __forceinline__ void bar_wait(int* gen, int ph, int t)
{
    if (t == 0) {
        while (atomicCAS(gen, -1, -1) < ph) __builtin_amdgcn_s_sleep(2);
    }
    __syncthreads();
    __threadfence();
}

// --------------------------------- fused gemm + Sinkhorn + finalize ---------
// 256 blocks x 256 threads, 1 block/CU. Block b owns cols [128b,128b+128).
// Phase A: MFMA G-tile into acc[4][8] -> store (x40) to G[b][row][col]
// (own-L2-resident, plain stores; acc dead after) -> barrier -> load
// tile[32] in R16 mapping (jq=t&31 col-quad, ig=t>>5, rows ig+8k) -> PIN.
// Phase C: R16's iteration loop VERBATIM. Phase D: fused finalize from tile.
__global__ __launch_bounds__(256, 1) void fused_k(
    const float* __restrict__ x, const float* __restrict__ y,
    float* __restrict__ G,
    float* __restrict__ su, const float* __restrict__ nx,
    const float* __restrict__ ny, float2* __restrict__ pms,
    float* __restrict__ prow, int* __restrict__ cnt, int* __restrict__ gen,
    unsigned* __restrict__ colerr, int* __restrict__ active,
    float* __restrict__ out)
{
    __shared__ __align__(16) char smem[63488];
    __shared__ int lastf;
    // gemm-phase region
    float4* xs4 = (float4*)smem;                  // [256 rows][8 slots] 32768B
    ushort* ys0 = (ushort*)(smem + 32768);        // [128][40] 10240B
    ushort* ys1 = (ushort*)(smem + 43008);
    ushort* ys2 = (ushort*)(smem + 53248);        // ends 63488
    // iteration/finalize region (alive after Phase A)
    float* su_lds = (float*)smem;                 // 256f  @0
    float* mm    = (float*)(smem + 1024);         // [8][128] 4096B -> 5120
    float* ss    = (float*)(smem + 5120);         // [8][128] -> 9216
    float* Mcol  = (float*)(smem + 9216);         // 128f -> 9728
    float* Wlds  = (float*)(smem + 9728);         // 128f -> 10240
    float* ecol  = (float*)(smem + 10240);        // 128f -> 10752
    float* Rlds  = (float*)(smem + 10752);        // 256f -> 11776
    float* errb  = (float*)(smem + 11776);        // 128f -> 12288
    float* nxl   = (float*)(smem + 12288);        // 256f -> 13312
    float* nyl   = (float*)(smem + 13312);        // 128f -> 13824
    float* pq    = (float*)(smem + 13824);        // [256][33]f 33792B -> 47616

    const int t   = threadIdx.x;
    const int b   = blockIdx.x;
    const int w   = t >> 6, ln = t & 63, q = ln >> 4, l15 = ln & 15;
    const int jq  = t & 31, ig = t >> 5;
    const int c0  = jq << 2;
    const int jy0 = b << 7;
    int ph = 1;

    const float4* x4 = (const float4*)x;
    const float4* y4 = (const float4*)y;

    // ================= Phase A: G-tile by MFMA (proven R18 code) ==========
    {
        f32x4 acc[4][8];
#pragma unroll
        for (int mi = 0; mi < 4; ++mi)
#pragma unroll
            for (int nj = 0; nj < 8; ++nj) acc[mi][nj] = (f32x4){0.f, 0.f, 0.f, 0.f};

        for (int kc = 0; kc < 12; ++kc) {
            __syncthreads();
            // stage x: 256 rows x 8 float4-slots, XOR-swizzled (slot ^= row&7)
#pragma unroll
            for (int p = 0; p < 8; ++p) {
                const int f = (p << 8) + t;          // 0..2047
                const int r = f >> 3, c4 = f & 7;
                xs4[(r << 3) + (c4 ^ (r & 7))] = x4[r * 96 + (kc << 3) + c4];
            }
            // stage y slab rows [128b,128b+128) with 3-way bf16 split
#pragma unroll
            for (int p = 0; p < 4; ++p) {
                const int f = (p << 8) + t;          // 0..1023
                const int r = f >> 3, c4 = f & 7;
                float4 vy = y4[(size_t)(jy0 + r) * 96 + (kc << 3) + c4];
                ushort a0,a1,a2,b0,b1,b2,g0,g1,g2,d0,d1,d2;
                split3(vy.x, a0,a1,a2); split3(vy.y, b0,b1,b2);
                split3(vy.z, g0,g1,g2); split3(vy.w, d0,d1,d2);
                *(ushort4*)&ys0[r * 40 + (c4 << 2)] = make_ushort4(a0,b0,g0,d0);
                *(ushort4*)&ys1[r * 40 + (c4 << 2)] = make_ushort4(a1,b1,g1,d1);
                *(ushort4*)&ys2[r * 40 + (c4 << 2)] = make_ushort4(a2,b2,g2,d2);
            }
            __syncthreads();

            // A fragments: row = 64w + 16mi + l15, k-offset q*8
            union U8 { ushort u[8]; bf16x8 v; };
            bf16x8 A0[4], A1[4], A2[4];
#pragma unroll
            for (int mi = 0; mi < 4; ++mi) {
                const int row = (w << 6) + (mi << 4) + l15;
                const int base = row << 3;
                float4 xa = xs4[base + (((q << 1) + 0) ^ (row & 7))];
                float4 xb = xs4[base + (((q << 1) + 1) ^ (row & 7))];
                U8 u0, u1, u2;
                split3(xa.x, u0.u[0], u1.u[0], u2.u[0]);
                split3(xa.y, u0.u[1], u1.u[1], u2.u[1]);
                split3(xa.z, u0.u[2], u1.u[2], u2.u[2]);
                split3(xa.w, u0.u[3], u1.u[3], u2.u[3]);
                split3(xb.x, u0.u[4], u1.u[4], u2.u[4]);
                split3(xb.y, u0.u[5], u1.u[5], u2.u[5]);
                split3(xb.z, u0.u[6], u1.u[6], u2.u[6]);
                split3(xb.w, u0.u[7], u1.u[7], u2.u[7]);
                A0[mi] = u0.v; A1[mi] = u1.v; A2[mi] = u2.v;
            }
#pragma unroll
            for (int nj = 0; nj < 8; ++nj) {
                const int off = ((nj << 4) + l15) * 40 + (q << 3);
                bf16x8 B0 = *(const bf16x8*)&ys0[off];
                bf16x8 B1 = *(const bf16x8*)&ys1[off];
                bf16x8 B2 = *(const bf16x8*)&ys2[off];
#pragma unroll
                for (int mi = 0; mi < 4; ++mi) {
                    f32x4 c = acc[mi][nj];
                    c = __builtin_amdgcn_mfma_f32_16x16x32_bf16(A0[mi], B0, c, 0, 0, 0);
                    c = __builtin_amdgcn_mfma_f32_16x16x32_bf16(A0[mi], B1, c, 0, 0, 0);
                    c = __builtin_amdgcn_mfma_f32_16x16x32_bf16(A1[mi], B0, c, 0, 0, 0);
                    c = __builtin_amdgcn_mfma_f32_16x16x32_bf16(A1[mi], B1, c, 0, 0, 0);
                    c = __builtin_amdgcn_mfma_f32_16x16x32_bf16(A0[mi], B2, c, 0, 0, 0);
                    c = __builtin_amdgcn_mfma_f32_16x16x32_bf16(A2[mi], B0, c, 0, 0, 0);
                    acc[mi][nj] = c;
                }
            }
        }

        // store acc (x40) to G[b][row][col] — own-L2 resident, plain stores
#pragma unroll
        for (int mi = 0; mi < 4; ++mi) {
#pragma unroll
            for (int r = 0; r < 4; ++r) {
                const int R = (w << 6) + (mi << 4) + (q << 2) + r;
                float* grow = G + ((size_t)b << 15) + (size_t)R * 128;
#pragma unroll
                for (int nj = 0; nj < 8; ++nj)
                    grow[(nj << 4) + l15] = 40.f * acc[mi][nj][r];
            }
        }
    }   // acc dead here

    __syncthreads();   // stores drained (vmcnt(0) before barrier) + staging dead

    // ---- load tile in R16 mapping: rows ig+8k, float4-col jq ----
    const float4* G4 = (const float4*)G;
    float4 tile[32];
#pragma unroll
    for (int k = 0; k < 32; ++k) {
        const int i = ig + (k << 3);
        tile[k] = G4[((size_t)b << 13) + (i << 5) + jq];
    }
#pragma unroll
    for (int k = 0; k < 32; ++k) PIN4(tile[k]);

    su_lds[t] = su[t];               // su0 = -20*|x|^2
    __syncthreads();

    // ================= Phase C: iterations (R16 verbatim) =================
    // ---- iteration 1 (log-safe, exact lse) ----
    {
        float m0=-INFINITY,m1=-INFINITY,m2=-INFINITY,m3=-INFINITY;
#pragma unroll
        for (int k = 0; k < 32; ++k) {
            const float sk = su_lds[ig + (k << 3)];
            m0=fmaxf(m0,tile[k].x+sk); m1=fmaxf(m1,tile[k].y+sk);
            m2=fmaxf(m2,tile[k].z+sk); m3=fmaxf(m3,tile[k].w+sk);
        }
        float s0=0.f,s1=0.f,s2=0.f,s3=0.f;
#pragma unroll
        for (int k = 0; k < 32; ++k) {
            const float sk = su_lds[ig + (k << 3)];
            s0+=__expf(tile[k].x+sk-m0); s1+=__expf(tile[k].y+sk-m1);
            s2+=__expf(tile[k].z+sk-m2); s3+=__expf(tile[k].w+sk-m3);
        }
        mm[ig*128+c0+0]=m0; ss[ig*128+c0+0]=s0;
        mm[ig*128+c0+1]=m1; ss[ig*128+c0+1]=s1;
        mm[ig*128+c0+2]=m2; ss[ig*128+c0+2]=s2;
        mm[ig*128+c0+3]=m3; ss[ig*128+c0+3]=s3;
        __syncthreads();
        if (t < 128) {
            float m=-INFINITY, s=0.f;
#pragma unroll
            for (int g = 0; g < 8; ++g) {
                float pmv=mm[g*128+t], psv=ss[g*128+t];
                float nm=fmaxf(m,pmv);
                s = s*__expf(m-nm) + psv*__expf(pmv-nm);
                m = nm;
            }
            Wlds[t] = LOG_B - (m + __logf(s));
        }
        __syncthreads();
    }
    // row pass (exact, two sweeps): rowmax then expsum, cross-block lse
    {
#pragma unroll
        for (int k = 0; k < 32; ++k) {
            const int i = ig + (k << 3);
            float a0=tile[k].x+Wlds[c0], a1=tile[k].y+Wlds[c0+1];
            float a2=tile[k].z+Wlds[c0+2], a3=tile[k].w+Wlds[c0+3];
            pq[i*33+jq] = fmaxf(fmaxf(a0,a1), fmaxf(a2,a3));
        }
        __syncthreads();
        {
            float R=-INFINITY;
#pragma unroll
            for (int qq = 0; qq < 32; ++qq) R = fmaxf(R, pq[t*33+qq]);
            Rlds[t] = R;
        }
        __syncthreads();
#pragma unroll
        for (int k = 0; k < 32; ++k) {
            const int i = ig + (k << 3);
            const float Rr = Rlds[i];
            float s = __expf(tile[k].x+Wlds[c0]-Rr)   + __expf(tile[k].y+Wlds[c0+1]-Rr)
                    + __expf(tile[k].z+Wlds[c0+2]-Rr) + __expf(tile[k].w+Wlds[c0+3]-Rr);
            pq[i*33+jq] = s;
        }
        __syncthreads();
        {
            float s = 0.f;
#pragma unroll
            for (int qq = 0; qq < 32; ++qq) s += pq[t*33+qq];
            pms[(b << 8) + t] = make_float2(Rlds[t], s);
        }
    }
    if (bar_arrive(cnt, ph, t, &lastf)) {
        __threadfence();
        float m=-INFINITY, s=0.f;
        for (int p = 0; p < 256; ++p) {
            float2 v = pms[(p << 8) + t];
            float nm = fmaxf(m, v.x);
            s = s*__expf(m-nm) + v.y*__expf(v.x-nm);
            m = nm;
        }
        su[t] = LOG_A - (m + __logf(s));
        bar_release(gen, ph, t);
    }
    bar_wait(gen, ph, t); ++ph;
    su_lds[t] = su[t];
    __syncthreads();

    // ---- convergence check #1 (ref cpt_n=1): col marginal err vs b ----
    int act;
    {
        float m0=-INFINITY,m1=-INFINITY,m2=-INFINITY,m3=-INFINITY;
#pragma unroll
        for (int k = 0; k < 32; ++k) {
            const float sk = su_lds[ig + (k << 3)];
            m0=fmaxf(m0,tile[k].x+sk); m1=fmaxf(m1,tile[k].y+sk);
            m2=fmaxf(m2,tile[k].z+sk); m3=fmaxf(m3,tile[k].w+sk);
        }
        float s0=0.f,s1=0.f,s2=0.f,s3=0.f;
#pragma unroll
        for (int k = 0; k < 32; ++k) {
            const float sk = su_lds[ig + (k << 3)];
            s0+=__expf(tile[k].x+sk-m0); s1+=__expf(tile[k].y+sk-m1);
            s2+=__expf(tile[k].z+sk-m2); s3+=__expf(tile[k].w+sk-m3);
        }
        mm[ig*128+c0+0]=m0; ss[ig*128+c0+0]=s0;
        mm[ig*128+c0+1]=m1; ss[ig*128+c0+1]=s1;
        mm[ig*128+c0+2]=m2; ss[ig*128+c0+2]=s2;
        mm[ig*128+c0+3]=m3; ss[ig*128+c0+3]=s3;
        __syncthreads();
        if (t < 128) {
            float m=-INFINITY, s=0.f;
#pragma unroll
            for (int g = 0; g < 8; ++g) {
                float pmv=mm[g*128+t], psv=ss[g*128+t];
                float nm=fmaxf(m,pmv);
                s = s*__expf(m-nm) + psv*__expf(pmv-nm);
                m = nm;
            }
            errb[t] = fabsf(__expf((m + __logf(s)) + Wlds[t]) - BVAL);
        }
        __syncthreads();
        for (int n = 64; n; n >>= 1) {
            if (t < n) errb[t] = fmaxf(errb[t], errb[t + n]);
            __syncthreads();
        }
        if (t == 0) atomicMax(&colerr[0], __float_as_uint(errb[0]));
        if (bar_arrive(cnt, ph, t, &lastf)) {
            if (t == 0) {
                unsigned e = atomicMax(&colerr[0], 0u);
                active[0] = (__uint_as_float(e) > 0.005f) ? 1 : 0;
            }
            bar_release(gen, ph, t);
        }
        bar_wait(gen, ph, t); ++ph;
        act = active[0];
    }

    // ---- fast iterations 2..100 (E-reuse, R16 verbatim) ----
    if (act) {
#pragma unroll 1
        for (int tt = 2; tt <= 100; ++tt) {
            // col pass: true col max
            {
                float m0=-INFINITY,m1=-INFINITY,m2=-INFINITY,m3=-INFINITY;
#pragma unroll
                for (int k = 0; k < 32; ++k) {
                    const float sk = su_lds[ig + (k << 3)];
                    m0=fmaxf(m0,tile[k].x+sk); m1=fmaxf(m1,tile[k].y+sk);
                    m2=fmaxf(m2,tile[k].z+sk); m3=fmaxf(m3,tile[k].w+sk);
                }
                mm[ig*128+c0+0]=m0; mm[ig*128+c0+1]=m1;
                mm[ig*128+c0+2]=m2; mm[ig*128+c0+3]=m3;
                __syncthreads();
                if (t < 128) {
                    float m=-INFINITY;
#pragma unroll
                    for (int g = 0; g < 8; ++g) m = fmaxf(m, mm[g*128+t]);
                    Mcol[t] = m;
                }
                __syncthreads();
            }
            float4 E[32];
            {
                const float Mc0=Mcol[c0], Mc1=Mcol[c0+1], Mc2=Mcol[c0+2], Mc3=Mcol[c0+3];
                float s0=0.f,s1=0.f,s2=0.f,s3=0.f;
#pragma unroll
                for (int k = 0; k < 32; ++k) {
                    const float sk = su_lds[ig + (k << 3)];
                    E[k].x=__expf(tile[k].x+sk-Mc0); s0+=E[k].x;
                    E[k].y=__expf(tile[k].y+sk-Mc1); s1+=E[k].y;
                    E[k].z=__expf(tile[k].z+sk-Mc2); s2+=E[k].z;
                    E[k].w=__expf(tile[k].w+sk-Mc3); s3+=E[k].w;
                }
                ss[ig*128+c0+0]=s0; ss[ig*128+c0+1]=s1;
                ss[ig*128+c0+2]=s2; ss[ig*128+c0+3]=s3;
                __syncthreads();
                if (t < 128) {
                    float ssum = 0.f;
#pragma unroll
                    for (int g = 0; g < 8; ++g) ssum += ss[g*128+t];
                    Wlds[t] = LOG_B - (Mcol[t] + __logf(ssum));
                    ecol[t] = 1.0f / ssum;
                }
                __syncthreads();
            }
            // row pass: partial = dot(E_rowslice, 1/S)
            {
                const float e0=ecol[c0], e1=ecol[c0+1], e2=ecol[c0+2], e3=ecol[c0+3];
#pragma unroll
                for (int k = 0; k < 32; ++k) {
                    const int i = ig + (k << 3);
                    pq[i*33+jq] = E[k].x*e0 + E[k].y*e1 + E[k].z*e2 + E[k].w*e3;
                }
                __syncthreads();
                float s = 0.f;
#pragma unroll
                for (int qq = 0; qq < 32; ++qq) s += pq[t*33+qq];
                prow[(b << 8) + t] = s;
            }
            if (bar_arrive(cnt, ph, t, &lastf)) {
                __threadfence();
                float tot = 0.f;
                for (int p = 0; p < 256; ++p) tot += prow[(p << 8) + t];
                su[t] = (LOG_A - LOG_B) + su_lds[t] - __logf(tot);
                bar_release(gen, ph, t);
            }
            bar_wait(gen, ph, t); ++ph;
            su_lds[t] = su[t];
            __syncthreads();

            if (tt == 51) {
                // convergence check #2 (ref cpt_n=51)
                float m0=-INFINITY,m1=-INFINITY,m2=-INFINITY,m3=-INFINITY;
#pragma unroll
                for (int k = 0; k < 32; ++k) {
                    const float sk = su_lds[ig + (k << 3)];
                    m0=fmaxf(m0,tile[k].x+sk); m1=fmaxf(m1,tile[k].y+sk);
                    m2=fmaxf(m2,tile[k].z+sk); m3=fmaxf(m3,tile[k].w+sk);
                }
                float s0=0.f,s1=0.f,s2=0.f,s3=0.f;
#pragma unroll
                for (int k = 0; k < 32; ++k) {
                    const float sk = su_lds[ig + (k << 3)];
                    s0+=__expf(tile[k].x+sk-m0); s1+=__expf(tile[k].y+sk-m1);
                    s2+=__expf(tile[k].z+sk-m2); s3+=__expf(tile[k].w+sk-m3);
                }
                mm[ig*128+c0+0]=m0; ss[ig*128+c0+0]=s0;
                mm[ig*128+c0+1]=m1; ss[ig*128+c0+1]=s1;
                mm[ig*128+c0+2]=m2; ss[ig*128+c0+2]=s2;
                mm[ig*128+c0+3]=m3; ss[ig*128+c0+3]=s3;
                __syncthreads();
                if (t < 128) {
                    float m=-INFINITY, s=0.f;
#pragma unroll
                    for (int g = 0; g < 8; ++g) {
                        float pmv=mm[g*128+t], psv=ss[g*128+t];
                        float nm=fmaxf(m,pmv);
                        s = s*__expf(m-nm) + psv*__expf(pmv-nm);
                        m = nm;
                    }
                    errb[t] = fabsf(__expf((m + __logf(s)) + Wlds[t]) - BVAL);
                }
                __syncthreads();
                for (int n = 64; n; n >>= 1) {
                    if (t < n) errb[t] = fmaxf(errb[t], errb[t + n]);
                    __syncthreads();
                }
                if (t == 0) atomicMax(&colerr[1], __float_as_uint(errb[0]));
                if (bar_arrive(cnt, ph, t, &lastf)) {
                    if (t == 0) {
                        unsigned e = atomicMax(&colerr[1], 0u);
                        active[0] = (__uint_as_float(e) > 0.005f) ? 1 : 0;
                    }
                    bar_release(gen, ph, t);
                }
                bar_wait(gen, ph, t); ++ph;
                if (active[0] == 0) break;
            }
        }
    }

    // ================= Phase D: fused finalize (from tile) ================
    nxl[t] = nx[t];
    if (t < 128) nyl[t] = ny[jy0 + t];
    __syncthreads();

    const float Wc0 = Wlds[c0+0], Wc1 = Wlds[c0+1], Wc2 = Wlds[c0+2], Wc3 = Wlds[c0+3];
    const float ny0 = nyl[c0+0], ny1 = nyl[c0+1], ny2 = nyl[c0+2], ny3 = nyl[c0+3];
    float accl = 0.f;
#pragma unroll 4
    for (int k = 0; k < 32; ++k) {
        const int i = ig + (k << 3);
        const float si = su_lds[i], nxi = nxl[i];
        const float g0 = tile[k].x, g1 = tile[k].y, g2 = tile[k].z, g3 = tile[k].w;
        float v0 = __expf(g0 + si + Wc0);
        float v1 = __expf(g1 + si + Wc1);
        float v2 = __expf(g2 + si + Wc2);
        float v3 = __expf(g3 + si + Wc3);
        float* o = out + 1 + (size_t)i * 32768 + jy0 + c0;
        __builtin_nontemporal_store(v0, o + 0);
        __builtin_nontemporal_store(v1, o + 1);
        __builtin_nontemporal_store(v2, o + 2);
        __builtin_nontemporal_store(v3, o + 3);
        accl += v0 * (nxi + ny0 - 0.05f * g0) +
                v1 * (nxi + ny1 - 0.05f * g1) +
                v2 * (nxi + ny2 - 0.05f * g2) +
                v3 * (nxi + ny3 - 0.05f * g3);
    }
    for (int off = 32; off; off >>= 1) accl += __shfl_down(accl, off);
    if (ln == 0) errb[w] = accl;
    __syncthreads();
    if (t == 0) atomicAdd(out, errb[0] + errb[1] + errb[2] + errb[3]);
}

// ---------------------------------------------------------------- host ------
extern "C" void kernel_launch(void* const* d_in, const int* in_sizes, int n_in,
                              void* d_out, int out_size, void* d_ws, size_t ws_size,
                              hipStream_t stream)
{
    const float* x = (const float*)d_in[0];   // [256, 384]
    const float* y = (const float*)d_in[1];   // [32768, 384]
    float* out = (float*)d_out;               // [1 + 256*32768]

    float* ws   = (float*)d_ws;
    float* G    = ws;                              // 8388608 (tiled [256][256][128])
    float* su   = G + 8388608;                     // 256
    float* nx   = su + 256;                        // 256
    float* ny   = nx + 256;                        // 32768
    float2* pms = (float2*)(ny + 32768);           // 65536 float2
    float* prow = (float*)(pms + 65536);           // 65536
    unsigned* colerr = (unsigned*)(prow + 65536);  // 2
    int* active   = (int*)(colerr + 2);            // 1
    int* counters = active + 1;                    // 4096 (barrier slots + gen)
    int* gen      = counters + 3000;

    init_k<<<8257, 256, 0, stream>>>(x, y, nx, ny, su, colerr, active, counters, out);
    fused_k<<<256, 256, 0, stream>>>(x, y, G, su, nx, ny, pms, prow,
                                     counters, gen, colerr, active, out);
}

// Round 13
// 337.393 us; speedup vs baseline: 1.0314x; 1.0314x over previous
//
#include <hip/hip_runtime.h>
#include <math.h>

// ---------------------------------------------------------------------------
// Sinkhorn ETP (FASTopic) on MI355X.
// n=256 topics, m=32768 words, D=384.
//
//   log_K0[i,j] = G[i,j] + su0[i] + sv0[j],  G = 40 * x@y^T
//   Per iteration:  W[j] = log_b - lse_i(G+su);  su'[i] = log_a - lse_j(G+W)
//   Final: transp[i,j] = exp(G+su[i]+W[j]); M = nx[i]+ny[j]-0.05*G;
//          loss = sum(transp*M)
//
// R16 (CHAMPION 383->308): persistent sink_loop (tile in 128 pinned VGPRs,
// device-scope generation barrier, fused convergence; 76us G-load tax +
// ~1.8us/iter). R17-R20 (all FAIL, 326-348): every gemm-fusion variant -
// layout-conversion spill (R17), slow fragment-layout iteration (R18/R19,
// allocator silently remats), in-kernel exchange missing L2 because y
// streaming evicts fresh G + write-allocate (R20, FETCH+32MB WRITE+57MB).
// CLOSED: G transiting memory costs ~76us at ANY producer->loop boundary;
// avoiding memory forces slow layouts. gemm stays a separate kernel.
//
// R21: R16 restored verbatim + the one uncontaminated fusion piece:
// finalize fused into sink_loop's tail (Phase D reads the pinned tile +
// Wlds/su_lds, writes transp+loss; no conversion, no co-liveness, no
// barrier). Deletes finalize_k's 32MB G re-read + one dispatch.
// Predicted: 3 dispatches, sink_loop ~180us (169 + D~10), WRITE ~46MB
// (no-spill check), total ~285-295. Falsifier: sink_loop>195 or WRITE>>60MB
// -> Phase D pressure hurt the loop -> pure R16 4-kernel is the plateau.
// ---------------------------------------------------------------------------

#define N_TOPIC 256
#define N_WORD  32768

static constexpr float LOG_A = -5.545177444479562f;    // log(1/256 + 1e-30)
static constexpr float LOG_B = -10.397207708399179f;   // log(1/32768 + 1e-30)
static constexpr float BVAL  = 3.0517578125e-05f;      // 1/32768

typedef float f32x4 __attribute__((ext_vector_type(4)));
typedef short bf16x8 __attribute__((ext_vector_type(8)));

// Keep a float4's lanes pinned in VGPRs (opaque use+def; no remat).
#define PIN4(v) asm volatile("" : "+v"((v).x), "+v"((v).y), "+v"((v).z), "+v"((v).w))

// ---------------------------------------------------------------- init ------
__global__ __launch_bounds__(256) void init_k(
    const float* __restrict__ x, const float* __restrict__ y,
    float* __restrict__ nx, float* __restrict__ ny, float* __restrict__ su,
    unsigned* __restrict__ colerr, int* __restrict__ active,
    int* __restrict__ counters, float* __restrict__ out)
{
    const int b = blockIdx.x, t = threadIdx.x;
    const int w = t >> 6, l = t & 63;
    if (b < 8192) {                       // ||y_j||^2, 4 rows/block (wave per row)
        const int r = (b << 2) + w;
        const float4* y4 = (const float4*)y;
        float4 v = y4[r * 96 + l];
        float s = v.x * v.x + v.y * v.y + v.z * v.z + v.w * v.w;
        if (l < 32) {
            float4 u = y4[r * 96 + 64 + l];
            s += u.x * u.x + u.y * u.y + u.z * u.z + u.w * u.w;
        }
        for (int off = 32; off; off >>= 1) s += __shfl_down(s, off);
        if (l == 0) ny[r] = s;
    } else if (b < 8256) {                // ||x_i||^2 and su0 = -20*nx
        const int r = ((b - 8192) << 2) + w;
        const float4* x4 = (const float4*)x;
        float4 v = x4[r * 96 + l];
        float s = v.x * v.x + v.y * v.y + v.z * v.z + v.w * v.w;
        if (l < 32) {
            float4 u = x4[r * 96 + 64 + l];
            s += u.x * u.x + u.y * u.y + u.z * u.z + u.w * u.w;
        }
        for (int off = 32; off; off >>= 1) s += __shfl_down(s, off);
        if (l == 0) { nx[r] = s; su[r] = -20.f * s; }
    } else {
        for (int k = t; k < 4096; k += 256) counters[k] = 0;
        if (t == 0) { colerr[0] = 0u; colerr[1] = 0u; active[0] = 1; out[0] = 0.f; }
    }
}

// ---------------------------------------------------------------- gemm ------
// Exact 3-way bf16 truncation split: v = b0 + b1 + b2 (+ r3, |r3|<=2^-27|v|).
static __device__ __forceinline__ void split3(float v, ushort& h0, ushort& h1, ushort& h2)
{
    unsigned u0 = __float_as_uint(v);
    h0 = (ushort)(u0 >> 16);
    float r1 = v - __uint_as_float(u0 & 0xFFFF0000u);
    unsigned u1 = __float_as_uint(r1);
    h1 = (ushort)(u1 >> 16);
    float r2 = r1 - __uint_as_float(u1 & 0xFFFF0000u);
    h2 = (ushort)(__float_as_uint(r2) >> 16);
}

// Block tile 128i x 128j, K-chunks of 32, grid (256 jb, 2 ib) = 512 blocks.
// Stores to tile layout [tile=j/128][i][j%128]: sink_loop block jb owns tile jb.
__global__ __launch_bounds__(256, 1) void gemm_k(
    const float* __restrict__ x, const float* __restrict__ y, float* __restrict__ G)
{
    __shared__ __align__(16) ushort xs0[5120], xs1[5120], xs2[5120];
    __shared__ __align__(16) ushort ys0[5120], ys1[5120], ys2[5120];

    const int t   = threadIdx.x;
    const int jb  = blockIdx.x << 7;   // 128-col slab
    const int ib  = blockIdx.y << 7;   // 128-row slab
    const int w   = t >> 6;            // wave 0..3
    const int ln  = t & 63;
    const int q   = ln >> 4;           // quad 0..3
    const int l15 = ln & 15;

    const float4* x4 = (const float4*)x;
    const float4* y4 = (const float4*)y;

    f32x4 acc[2][8];
#pragma unroll
    for (int mi = 0; mi < 2; ++mi)
#pragma unroll
        for (int nj = 0; nj < 8; ++nj) acc[mi][nj] = (f32x4){0.f, 0.f, 0.f, 0.f};

    for (int kc = 0; kc < 12; ++kc) {
        __syncthreads();
#pragma unroll
        for (int p = 0; p < 4; ++p) {
            const int f  = (t << 2) + p;       // 0..1023 float4 slots
            const int r  = f >> 3, c4 = f & 7; // row, k-quad
            const int o  = r * 40 + (c4 << 2);
            float4 vx = x4[(ib + r) * 96 + (kc << 3) + c4];
            ushort a0,a1,a2,b0,b1,b2,c0,c1,c2,d0,d1,d2;
            split3(vx.x, a0,a1,a2); split3(vx.y, b0,b1,b2);
            split3(vx.z, c0,c1,c2); split3(vx.w, d0,d1,d2);
            *(ushort4*)&xs0[o] = make_ushort4(a0,b0,c0,d0);
            *(ushort4*)&xs1[o] = make_ushort4(a1,b1,c1,d1);
            *(ushort4*)&xs2[o] = make_ushort4(a2,b2,c2,d2);
            float4 vy = y4[(jb + r) * 96 + (kc << 3) + c4];
            split3(vy.x, a0,a1,a2); split3(vy.y, b0,b1,b2);
            split3(vy.z, c0,c1,c2); split3(vy.w, d0,d1,d2);
            *(ushort4*)&ys0[o] = make_ushort4(a0,b0,c0,d0);
            *(ushort4*)&ys1[o] = make_ushort4(a1,b1,c1,d1);
            *(ushort4*)&ys2[o] = make_ushort4(a2,b2,c2,d2);
        }
        __syncthreads();

        bf16x8 A[3][2];
#pragma unroll
        for (int mi = 0; mi < 2; ++mi) {
            const int off = ((w << 5) + (mi << 4) + l15) * 40 + (q << 3);
            A[0][mi] = *(const bf16x8*)&xs0[off];
            A[1][mi] = *(const bf16x8*)&xs1[off];
            A[2][mi] = *(const bf16x8*)&xs2[off];
        }
#pragma unroll
        for (int nj = 0; nj < 8; ++nj) {
            const int off = ((nj << 4) + l15) * 40 + (q << 3);
            bf16x8 B0 = *(const bf16x8*)&ys0[off];
            bf16x8 B1 = *(const bf16x8*)&ys1[off];
            bf16x8 B2 = *(const bf16x8*)&ys2[off];
#pragma unroll
            for (int mi = 0; mi < 2; ++mi) {
                f32x4 c = acc[mi][nj];
                c = __builtin_amdgcn_mfma_f32_16x16x32_bf16(A[0][mi], B0, c, 0, 0, 0);
                c = __builtin_amdgcn_mfma_f32_16x16x32_bf16(A[0][mi], B1, c, 0, 0, 0);
                c = __builtin_amdgcn_mfma_f32_16x16x32_bf16(A[1][mi], B0, c, 0, 0, 0);
                c = __builtin_amdgcn_mfma_f32_16x16x32_bf16(A[1][mi], B1, c, 0, 0, 0);
                c = __builtin_amdgcn_mfma_f32_16x16x32_bf16(A[0][mi], B2, c, 0, 0, 0);
                c = __builtin_amdgcn_mfma_f32_16x16x32_bf16(A[2][mi], B0, c, 0, 0, 0);
                acc[mi][nj] = c;
            }
        }
    }
    // Tiled store: (gi, gj) -> G[(gj>>7)*32768 + gi*128 + (gj&127)]
#pragma unroll
    for (int mi = 0; mi < 2; ++mi) {
        const int gi0 = ib + (w << 5) + (mi << 4) + (q << 2);
#pragma unroll
        for (int nj = 0; nj < 8; ++nj) {
            float* base = &G[(size_t)blockIdx.x * 32768 + (size_t)gi0 * 128
                             + (nj << 4) + l15];
#pragma unroll
            for (int r = 0; r < 4; ++r)
                base[r * 128] = 40.f * acc[mi][nj][r];
        }
    }
}

// ----------------------------------------------- persistent barrier ---------
static __device__ __forceinline__ bool bar_arrive(int* cnt, int ph, int t, int* lastf)
{
    __threadfence();
    if (t == 0) *lastf = (atomicAdd(&cnt[ph], 1) == 255);
    __syncthreads();
    return *lastf != 0;
}
static __device__ __forceinline__ void bar_release(int* gen, int ph, int t)
{
    __threadfence();
    if (t == 0) atomicExch(gen, ph);
}
static __device__ __forceinline__ void bar_wait(int* gen, int ph, int t)
{
    if (t == 0) {
        while (atomicCAS(gen, -1, -1) < ph) __builtin_amdgcn_s_sleep(2);
    }
    __syncthreads();
    __threadfence();
}

// ------------------------- persistent Sinkhorn loop + fused finalize --------
// 256 blocks x 256 threads, 1 block/CU. Block b owns G-tile b: rows 0..255 x
// cols [128b, 128b+128), register-resident (float4 tile[32], pinned).
// Thread mapping: jq = t&31 (float4-col), ig = t>>5, rows i = ig + 8k.
// Phase D (R21): finalize fused — transp+loss from tile/Wlds/su_lds.
__global__ __launch_bounds__(256, 1) void sink_loop(
    const float* __restrict__ G, float* __restrict__ su,
    const float* __restrict__ nx, const float* __restrict__ ny,
    float2* __restrict__ pms, float* __restrict__ prow,
    int* __restrict__ cnt, int* __restrict__ gen,
    unsigned* __restrict__ colerr, int* __restrict__ active,
    float* __restrict__ out)
{
    __shared__ float su_lds[256];
    __shared__ float mm[1024];       // [8][128] col partials
    __shared__ float ss[1024];
    __shared__ float Mcol[128];
    __shared__ float Wlds[128];
    __shared__ float ecol[128];
    __shared__ float Rlds[256];
    __shared__ float pq[256 * 33];   // row partials (reused every pass)
    __shared__ float errb[128];
    __shared__ float nxl[256];
    __shared__ float nyl[128];
    __shared__ int lastf;

    const int t  = threadIdx.x;
    const int b  = blockIdx.x;
    const int jq = t & 31;
    const int ig = t >> 5;
    const int c0 = jq << 2;
    const int w  = t >> 6, ln = t & 63;
    const int jy0 = b << 7;
    int ph = 1;

    // ---- load tile (once, ever) ----
    const float4* G4 = (const float4*)G;
    float4 tile[32];
#pragma unroll
    for (int k = 0; k < 32; ++k) {
        const int i = ig + (k << 3);
        tile[k] = G4[((size_t)b << 13) + (i << 5) + jq];
    }
#pragma unroll
    for (int k = 0; k < 32; ++k) PIN4(tile[k]);

    su_lds[t] = su[t];               // su0 = -20*|x|^2
    __syncthreads();

    // ================= iteration 1 (log-safe, exact lse) =================
    {
        float m0=-INFINITY,m1=-INFINITY,m2=-INFINITY,m3=-INFINITY;
#pragma unroll
        for (int k = 0; k < 32; ++k) {
            const float sk = su_lds[ig + (k << 3)];
            m0=fmaxf(m0,tile[k].x+sk); m1=fmaxf(m1,tile[k].y+sk);
            m2=fmaxf(m2,tile[k].z+sk); m3=fmaxf(m3,tile[k].w+sk);
        }
        float s0=0.f,s1=0.f,s2=0.f,s3=0.f;
#pragma unroll
        for (int k = 0; k < 32; ++k) {
            const float sk = su_lds[ig + (k << 3)];
            s0+=__expf(tile[k].x+sk-m0); s1+=__expf(tile[k].y+sk-m1);
            s2+=__expf(tile[k].z+sk-m2); s3+=__expf(tile[k].w+sk-m3);
        }
        mm[ig*128+c0+0]=m0; ss[ig*128+c0+0]=s0;
        mm[ig*128+c0+1]=m1; ss[ig*128+c0+1]=s1;
        mm[ig*128+c0+2]=m2; ss[ig*128+c0+2]=s2;
        mm[ig*128+c0+3]=m3; ss[ig*128+c0+3]=s3;
        __syncthreads();
        if (t < 128) {
            float m=-INFINITY, s=0.f;
#pragma unroll
            for (int g = 0; g < 8; ++g) {
                float pmv=mm[g*128+t], psv=ss[g*128+t];
                float nm=fmaxf(m,pmv);
                s = s*__expf(m-nm) + psv*__expf(pmv-nm);
                m = nm;
            }
            Wlds[t] = LOG_B - (m + __logf(s));
        }
        __syncthreads();
    }
    // row pass (exact, two sweeps): rowmax then expsum, cross-block lse
    {
#pragma unroll
        for (int k = 0; k < 32; ++k) {
            const int i = ig + (k << 3);
            float a0=tile[k].x+Wlds[c0], a1=tile[k].y+Wlds[c0+1];
            float a2=tile[k].z+Wlds[c0+2], a3=tile[k].w+Wlds[c0+3];
            pq[i*33+jq] = fmaxf(fmaxf(a0,a1), fmaxf(a2,a3));
        }
        __syncthreads();
        {
            float R=-INFINITY;
#pragma unroll
            for (int qq = 0; qq < 32; ++qq) R = fmaxf(R, pq[t*33+qq]);
            Rlds[t] = R;
        }
        __syncthreads();
#pragma unroll
        for (int k = 0; k < 32; ++k) {
            const int i = ig + (k << 3);
            const float Rr = Rlds[i];
            float s = __expf(tile[k].x+Wlds[c0]-Rr)   + __expf(tile[k].y+Wlds[c0+1]-Rr)
                    + __expf(tile[k].z+Wlds[c0+2]-Rr) + __expf(tile[k].w+Wlds[c0+3]-Rr);
            pq[i*33+jq] = s;
        }
        __syncthreads();
        {
            float s = 0.f;
#pragma unroll
            for (int qq = 0; qq < 32; ++qq) s += pq[t*33+qq];
            pms[(b << 8) + t] = make_float2(Rlds[t], s);
        }
    }
    if (bar_arrive(cnt, ph, t, &lastf)) {
        __threadfence();
        float m=-INFINITY, s=0.f;
        for (int p = 0; p < 256; ++p) {
            float2 v = pms[(p << 8) + t];
            float nm = fmaxf(m, v.x);
            s = s*__expf(m-nm) + v.y*__expf(v.x-nm);
            m = nm;
        }
        su[t] = LOG_A - (m + __logf(s));
        bar_release(gen, ph, t);
    }
    bar_wait(gen, ph, t); ++ph;
    su_lds[t] = su[t];
    __syncthreads();

    // ---- convergence check #1 (ref cpt_n=1): col marginal err vs b ----
    int act;
    {
        float m0=-INFINITY,m1=-INFINITY,m2=-INFINITY,m3=-INFINITY;
#pragma unroll
        for (int k = 0; k < 32; ++k) {
            const float sk = su_lds[ig + (k << 3)];
            m0=fmaxf(m0,tile[k].x+sk); m1=fmaxf(m1,tile[k].y+sk);
            m2=fmaxf(m2,tile[k].z+sk); m3=fmaxf(m3,tile[k].w+sk);
        }
        float s0=0.f,s1=0.f,s2=0.f,s3=0.f;
#pragma unroll
        for (int k = 0; k < 32; ++k) {
            const float sk = su_lds[ig + (k << 3)];
            s0+=__expf(tile[k].x+sk-m0); s1+=__expf(tile[k].y+sk-m1);
            s2+=__expf(tile[k].z+sk-m2); s3+=__expf(tile[k].w+sk-m3);
        }
        mm[ig*128+c0+0]=m0; ss[ig*128+c0+0]=s0;
        mm[ig*128+c0+1]=m1; ss[ig*128+c0+1]=s1;
        mm[ig*128+c0+2]=m2; ss[ig*128+c0+2]=s2;
        mm[ig*128+c0+3]=m3; ss[ig*128+c0+3]=s3;
        __syncthreads();
        if (t < 128) {
            float m=-INFINITY, s=0.f;
#pragma unroll
            for (int g = 0; g < 8; ++g) {
                float pmv=mm[g*128+t], psv=ss[g*128+t];
                float nm=fmaxf(m,pmv);
                s = s*__expf(m-nm) + psv*__expf(pmv-nm);
                m = nm;
            }
            errb[t] = fabsf(__expf((m + __logf(s)) + Wlds[t]) - BVAL);
        }
        __syncthreads();
        for (int n = 64; n; n >>= 1) {
            if (t < n) errb[t] = fmaxf(errb[t], errb[t + n]);
            __syncthreads();
        }
        if (t == 0) atomicMax(&colerr[0], __float_as_uint(errb[0]));
        if (bar_arrive(cnt, ph, t, &lastf)) {
            if (t == 0) {
                unsigned e = atomicMax(&colerr[0], 0u);
                active[0] = (__uint_as_float(e) > 0.005f) ? 1 : 0;
            }
            bar_release(gen, ph, t);
        }
        bar_wait(gen, ph, t); ++ph;
        act = active[0];
    }

    // ================= fast iterations 2..100 (E-reuse) =================
    if (act) {
#pragma unroll 1
        for (int tt = 2; tt <= 100; ++tt) {
            // col pass: true col max, then E = exp(G+su-M), col sums S
            {
                float m0=-INFINITY,m1=-INFINITY,m2=-INFINITY,m3=-INFINITY;
#pragma unroll
                for (int k = 0; k < 32; ++k) {
                    const float sk = su_lds[ig + (k << 3)];
                    m0=fmaxf(m0,tile[k].x+sk); m1=fmaxf(m1,tile[k].y+sk);
                    m2=fmaxf(m2,tile[k].z+sk); m3=fmaxf(m3,tile[k].w+sk);
                }
                mm[ig*128+c0+0]=m0; mm[ig*128+c0+1]=m1;
                mm[ig*128+c0+2]=m2; mm[ig*128+c0+3]=m3;
                __syncthreads();
                if (t < 128) {
                    float m=-INFINITY;
#pragma unroll
                    for (int g = 0; g < 8; ++g) m = fmaxf(m, mm[g*128+t]);
                    Mcol[t] = m;
                }
                __syncthreads();
            }
            float4 E[32];
            {
                const float Mc0=Mcol[c0], Mc1=Mcol[c0+1], Mc2=Mcol[c0+2], Mc3=Mcol[c0+3];
                float s0=0.f,s1=0.f,s2=0.f,s3=0.f;
#pragma unroll
                for (int k = 0; k < 32; ++k) {
                    const float sk = su_lds[ig + (k << 3)];
                    E[k].x=__expf(tile[k].x+sk-Mc0); s0+=E[k].x;
                    E[k].y=__expf(tile[k].y+sk-Mc1); s1+=E[k].y;
                    E[k].z=__expf(tile[k].z+sk-Mc2); s2+=E[k].z;
                    E[k].w=__expf(tile[k].w+sk-Mc3); s3+=E[k].w;
                }
                ss[ig*128+c0+0]=s0; ss[ig*128+c0+1]=s1;
                ss[ig*128+c0+2]=s2; ss[ig*128+c0+3]=s3;
                __syncthreads();
                if (t < 128) {
                    float ssum = 0.f;
#pragma unroll
                    for (int g = 0; g < 8; ++g) ssum += ss[g*128+t];
                    Wlds[t] = LOG_B - (Mcol[t] + __logf(ssum));
                    ecol[t] = 1.0f / ssum;
                }
                __syncthreads();
            }
            // row pass: partial = dot(E_rowslice, 1/S)
            {
                const float e0=ecol[c0], e1=ecol[c0+1], e2=ecol[c0+2], e3=ecol[c0+3];
#pragma unroll
                for (int k = 0; k < 32; ++k) {
                    const int i = ig + (k << 3);
                    pq[i*33+jq] = E[k].x*e0 + E[k].y*e1 + E[k].z*e2 + E[k].w*e3;
                }
                __syncthreads();
                float s = 0.f;
#pragma unroll
                for (int qq = 0; qq < 32; ++qq) s += pq[t*33+qq];
                prow[(b << 8) + t] = s;
            }
            if (bar_arrive(cnt, ph, t, &lastf)) {
                __threadfence();
                float tot = 0.f;
                for (int p = 0; p < 256; ++p) tot += prow[(p << 8) + t];
                su[t] = (LOG_A - LOG_B) + su_lds[t] - __logf(tot);
                bar_release(gen, ph, t);
            }
            bar_wait(gen, ph, t); ++ph;
            su_lds[t] = su[t];
            __syncthreads();

            if (tt == 51) {
                // convergence check #2 (ref cpt_n=51)
                float m0=-INFINITY,m1=-INFINITY,m2=-INFINITY,m3=-INFINITY;
#pragma unroll
                for (int k = 0; k < 32; ++k) {
                    const float sk = su_lds[ig + (k << 3)];
                    m0=fmaxf(m0,tile[k].x+sk); m1=fmaxf(m1,tile[k].y+sk);
                    m2=fmaxf(m2,tile[k].z+sk); m3=fmaxf(m3,tile[k].w+sk);
                }
                float s0=0.f,s1=0.f,s2=0.f,s3=0.f;
#pragma unroll
                for (int k = 0; k < 32; ++k) {
                    const float sk = su_lds[ig + (k << 3)];
                    s0+=__expf(tile[k].x+sk-m0); s1+=__expf(tile[k].y+sk-m1);
                    s2+=__expf(tile[k].z+sk-m2); s3+=__expf(tile[k].w+sk-m3);
                }
                mm[ig*128+c0+0]=m0; ss[ig*128+c0+0]=s0;
                mm[ig*128+c0+1]=m1; ss[ig*128+c0+1]=s1;
                mm[ig*128+c0+2]=m2; ss[ig*128+c0+2]=s2;
                mm[ig*128+c0+3]=m3; ss[ig*128+c0+3]=s3;
                __syncthreads();
                if (t < 128) {
                    float m=-INFINITY, s=0.f;
#pragma unroll
                    for (int g = 0; g < 8; ++g) {
                        float pmv=mm[g*128+t], psv=ss[g*128+t];
                        float nm=fmaxf(m,pmv);
                        s = s*__expf(m-nm) + psv*__expf(pmv-nm);
                        m = nm;
                    }
                    errb[t] = fabsf(__expf((m + __logf(s)) + Wlds[t]) - BVAL);
                }
                __syncthreads();
                for (int n = 64; n; n >>= 1) {
                    if (t < n) errb[t] = fmaxf(errb[t], errb[t + n]);
                    __syncthreads();
                }
                if (t == 0) atomicMax(&colerr[1], __float_as_uint(errb[0]));
                if (bar_arrive(cnt, ph, t, &lastf)) {
                    if (t == 0) {
                        unsigned e = atomicMax(&colerr[1], 0u);
                        active[0] = (__uint_as_float(e) > 0.005f) ? 1 : 0;
                    }
                    bar_release(gen, ph, t);
                }
                bar_wait(gen, ph, t); ++ph;
                if (active[0] == 0) break;
            }
        }
    }

    // ================= Phase D: fused finalize (from tile) ================
    nxl[t] = nx[t];
    if (t < 128) nyl[t] = ny[jy0 + t];
    __syncthreads();

    const float Wc0 = Wlds[c0+0], Wc1 = Wlds[c0+1], Wc2 = Wlds[c0+2], Wc3 = Wlds[c0+3];
    const float ny0 = nyl[c0+0], ny1 = nyl[c0+1], ny2 = nyl[c0+2], ny3 = nyl[c0+3];
    float accl = 0.f;
#pragma unroll 4
    for (int k = 0; k < 32; ++k) {
        const int i = ig + (k << 3);
        const float si = su_lds[i], nxi = nxl[i];
        const float g0 = tile[k].x, g1 = tile[k].y, g2 = tile[k].z, g3 = tile[k].w;
        float v0 = __expf(g0 + si + Wc0);
        float v1 = __expf(g1 + si + Wc1);
        float v2 = __expf(g2 + si + Wc2);
        float v3 = __expf(g3 + si + Wc3);
        float* o = out + 1 + (size_t)i * 32768 + jy0 + c0;
        __builtin_nontemporal_store(v0, o + 0);
        __builtin_nontemporal_store(v1, o + 1);
        __builtin_nontemporal_store(v2, o + 2);
        __builtin_nontemporal_store(v3, o + 3);
        accl += v0 * (nxi + ny0 - 0.05f * g0) +
                v1 * (nxi + ny1 - 0.05f * g1) +
                v2 * (nxi + ny2 - 0.05f * g2) +
                v3 * (nxi + ny3 - 0.05f * g3);
    }
    for (int off = 32; off; off >>= 1) accl += __shfl_down(accl, off);
    if (ln == 0) errb[w] = accl;
    __syncthreads();
    if (t == 0) atomicAdd(out, errb[0] + errb[1] + errb[2] + errb[3]);
}

// ---------------------------------------------------------------- host ------
extern "C" void kernel_launch(void* const* d_in, const int* in_sizes, int n_in,
                              void* d_out, int out_size, void* d_ws, size_t ws_size,
                              hipStream_t stream)
{
    const float* x = (const float*)d_in[0];   // [256, 384]
    const float* y = (const float*)d_in[1];   // [32768, 384]
    float* out = (float*)d_out;               // [1 + 256*32768]

    float* ws   = (float*)d_ws;
    float* G    = ws;                              // 8388608 (tiled [256][256][128])
    float* su   = G + 8388608;                     // 256
    float* nx   = su + 256;                        // 256
    float* ny   = nx + 256;                        // 32768
    float2* pms = (float2*)(ny + 32768);           // 65536 float2
    float* prow = (float*)(pms + 65536);           // 65536
    unsigned* colerr = (unsigned*)(prow + 65536);  // 2
    int* active   = (int*)(colerr + 2);            // 1
    int* counters = active + 1;                    // 4096 (barrier slots + gen)
    int* gen      = counters + 3000;

    init_k<<<8257, 256, 0, stream>>>(x, y, nx, ny, su, colerr, active, counters, out);
    gemm_k<<<dim3(256, 2), 256, 0, stream>>>(x, y, G);
    sink_loop<<<256, 256, 0, stream>>>(G, su, nx, ny, pms, prow,
                                       counters, gen, colerr, active, out);
}

// Round 14
// 307.619 us; speedup vs baseline: 1.1312x; 1.0968x over previous
//
#include <hip/hip_runtime.h>
#include <math.h>

// ---------------------------------------------------------------------------
// Sinkhorn ETP (FASTopic) on MI355X.
// n=256 topics, m=32768 words, D=384.
//
//   log_K0[i,j] = G[i,j] + su0[i] + sv0[j],  G = 40 * x@y^T
//   Per iteration:  W[j] = log_b - lse_i(G+su);  su'[i] = log_a - lse_j(G+W)
//   Final: transp[i,j] = exp(G+su[i]+W[j]); M = nx[i]+ny[j]-0.05*G;
//          loss = sum(transp*M)
//
// R16 (CHAMPION 383->308): persistent sink_loop, tile in 128 pinned VGPRs
// (VGPR_Count 180, no spill), device barrier, fused convergence.
// R17-R20: all gemm-fusion variants fail (spill / slow fragment layout /
// L2 eviction). R21 (FAIL 337): fusing finalize that READS THE TILE extended
// the tile's live range into Phase D -> allocator flipped to spill-the-tile
// (VGPR 108 < 128, WRITE 101MB scratch round-trip) -> whole loop poisoned.
//
// R22: R16 loop bit-for-bit (proven allocation profile) + Phase D that
// RELOADS G from memory instead of touching tile. Tile's last use = loop's
// final pass (same liveness as R16); Phase D is a low-pressure tail. G is
// L3-resident after the initial load (iteration traffic ~13MB total) and
// per-block contiguous -> reload ~5-10us (finalize_k reading the same data
// was never in any top-5). Still deletes finalize_k's dispatch + boundary.
// Predicted: sink_loop VGPR ~180, WRITE ~46MB (spill check), FETCH ~17-20MB,
// dur ~180; total ~290-300. Falsifier: VGPR<128 or WRITE>>60MB -> tail
// fusion structurally impossible -> revert to pure R16 4-kernel (plateau).
// ---------------------------------------------------------------------------

#define N_TOPIC 256
#define N_WORD  32768

static constexpr float LOG_A = -5.545177444479562f;    // log(1/256 + 1e-30)
static constexpr float LOG_B = -10.397207708399179f;   // log(1/32768 + 1e-30)
static constexpr float BVAL  = 3.0517578125e-05f;      // 1/32768

typedef float f32x4 __attribute__((ext_vector_type(4)));
typedef short bf16x8 __attribute__((ext_vector_type(8)));

// Keep a float4's lanes pinned in VGPRs (opaque use+def; no remat).
#define PIN4(v) asm volatile("" : "+v"((v).x), "+v"((v).y), "+v"((v).z), "+v"((v).w))

// ---------------------------------------------------------------- init ------
__global__ __launch_bounds__(256) void init_k(
    const float* __restrict__ x, const float* __restrict__ y,
    float* __restrict__ nx, float* __restrict__ ny, float* __restrict__ su,
    unsigned* __restrict__ colerr, int* __restrict__ active,
    int* __restrict__ counters, float* __restrict__ out)
{
    const int b = blockIdx.x, t = threadIdx.x;
    const int w = t >> 6, l = t & 63;
    if (b < 8192) {                       // ||y_j||^2, 4 rows/block (wave per row)
        const int r = (b << 2) + w;
        const float4* y4 = (const float4*)y;
        float4 v = y4[r * 96 + l];
        float s = v.x * v.x + v.y * v.y + v.z * v.z + v.w * v.w;
        if (l < 32) {
            float4 u = y4[r * 96 + 64 + l];
            s += u.x * u.x + u.y * u.y + u.z * u.z + u.w * u.w;
        }
        for (int off = 32; off; off >>= 1) s += __shfl_down(s, off);
        if (l == 0) ny[r] = s;
    } else if (b < 8256) {                // ||x_i||^2 and su0 = -20*nx
        const int r = ((b - 8192) << 2) + w;
        const float4* x4 = (const float4*)x;
        float4 v = x4[r * 96 + l];
        float s = v.x * v.x + v.y * v.y + v.z * v.z + v.w * v.w;
        if (l < 32) {
            float4 u = x4[r * 96 + 64 + l];
            s += u.x * u.x + u.y * u.y + u.z * u.z + u.w * u.w;
        }
        for (int off = 32; off; off >>= 1) s += __shfl_down(s, off);
        if (l == 0) { nx[r] = s; su[r] = -20.f * s; }
    } else {
        for (int k = t; k < 4096; k += 256) counters[k] = 0;
        if (t == 0) { colerr[0] = 0u; colerr[1] = 0u; active[0] = 1; out[0] = 0.f; }
    }
}

// ---------------------------------------------------------------- gemm ------
// Exact 3-way bf16 truncation split: v = b0 + b1 + b2 (+ r3, |r3|<=2^-27|v|).
static __device__ __forceinline__ void split3(float v, ushort& h0, ushort& h1, ushort& h2)
{
    unsigned u0 = __float_as_uint(v);
    h0 = (ushort)(u0 >> 16);
    float r1 = v - __uint_as_float(u0 & 0xFFFF0000u);
    unsigned u1 = __float_as_uint(r1);
    h1 = (ushort)(u1 >> 16);
    float r2 = r1 - __uint_as_float(u1 & 0xFFFF0000u);
    h2 = (ushort)(__float_as_uint(r2) >> 16);
}

// Block tile 128i x 128j, K-chunks of 32, grid (256 jb, 2 ib) = 512 blocks.
// Stores to tile layout [tile=j/128][i][j%128]: sink_loop block jb owns tile jb.
__global__ __launch_bounds__(256, 1) void gemm_k(
    const float* __restrict__ x, const float* __restrict__ y, float* __restrict__ G)
{
    __shared__ __align__(16) ushort xs0[5120], xs1[5120], xs2[5120];
    __shared__ __align__(16) ushort ys0[5120], ys1[5120], ys2[5120];

    const int t   = threadIdx.x;
    const int jb  = blockIdx.x << 7;   // 128-col slab
    const int ib  = blockIdx.y << 7;   // 128-row slab
    const int w   = t >> 6;            // wave 0..3
    const int ln  = t & 63;
    const int q   = ln >> 4;           // quad 0..3
    const int l15 = ln & 15;

    const float4* x4 = (const float4*)x;
    const float4* y4 = (const float4*)y;

    f32x4 acc[2][8];
#pragma unroll
    for (int mi = 0; mi < 2; ++mi)
#pragma unroll
        for (int nj = 0; nj < 8; ++nj) acc[mi][nj] = (f32x4){0.f, 0.f, 0.f, 0.f};

    for (int kc = 0; kc < 12; ++kc) {
        __syncthreads();
#pragma unroll
        for (int p = 0; p < 4; ++p) {
            const int f  = (t << 2) + p;       // 0..1023 float4 slots
            const int r  = f >> 3, c4 = f & 7; // row, k-quad
            const int o  = r * 40 + (c4 << 2);
            float4 vx = x4[(ib + r) * 96 + (kc << 3) + c4];
            ushort a0,a1,a2,b0,b1,b2,c0,c1,c2,d0,d1,d2;
            split3(vx.x, a0,a1,a2); split3(vx.y, b0,b1,b2);
            split3(vx.z, c0,c1,c2); split3(vx.w, d0,d1,d2);
            *(ushort4*)&xs0[o] = make_ushort4(a0,b0,c0,d0);
            *(ushort4*)&xs1[o] = make_ushort4(a1,b1,c1,d1);
            *(ushort4*)&xs2[o] = make_ushort4(a2,b2,c2,d2);
            float4 vy = y4[(jb + r) * 96 + (kc << 3) + c4];
            split3(vy.x, a0,a1,a2); split3(vy.y, b0,b1,b2);
            split3(vy.z, c0,c1,c2); split3(vy.w, d0,d1,d2);
            *(ushort4*)&ys0[o] = make_ushort4(a0,b0,c0,d0);
            *(ushort4*)&ys1[o] = make_ushort4(a1,b1,c1,d1);
            *(ushort4*)&ys2[o] = make_ushort4(a2,b2,c2,d2);
        }
        __syncthreads();

        bf16x8 A[3][2];
#pragma unroll
        for (int mi = 0; mi < 2; ++mi) {
            const int off = ((w << 5) + (mi << 4) + l15) * 40 + (q << 3);
            A[0][mi] = *(const bf16x8*)&xs0[off];
            A[1][mi] = *(const bf16x8*)&xs1[off];
            A[2][mi] = *(const bf16x8*)&xs2[off];
        }
#pragma unroll
        for (int nj = 0; nj < 8; ++nj) {
            const int off = ((nj << 4) + l15) * 40 + (q << 3);
            bf16x8 B0 = *(const bf16x8*)&ys0[off];
            bf16x8 B1 = *(const bf16x8*)&ys1[off];
            bf16x8 B2 = *(const bf16x8*)&ys2[off];
#pragma unroll
            for (int mi = 0; mi < 2; ++mi) {
                f32x4 c = acc[mi][nj];
                c = __builtin_amdgcn_mfma_f32_16x16x32_bf16(A[0][mi], B0, c, 0, 0, 0);
                c = __builtin_amdgcn_mfma_f32_16x16x32_bf16(A[0][mi], B1, c, 0, 0, 0);
                c = __builtin_amdgcn_mfma_f32_16x16x32_bf16(A[1][mi], B0, c, 0, 0, 0);
                c = __builtin_amdgcn_mfma_f32_16x16x32_bf16(A[1][mi], B1, c, 0, 0, 0);
                c = __builtin_amdgcn_mfma_f32_16x16x32_bf16(A[0][mi], B2, c, 0, 0, 0);
                c = __builtin_amdgcn_mfma_f32_16x16x32_bf16(A[2][mi], B0, c, 0, 0, 0);
                acc[mi][nj] = c;
            }
        }
    }
    // Tiled store: (gi, gj) -> G[(gj>>7)*32768 + gi*128 + (gj&127)]
#pragma unroll
    for (int mi = 0; mi < 2; ++mi) {
        const int gi0 = ib + (w << 5) + (mi << 4) + (q << 2);
#pragma unroll
        for (int nj = 0; nj < 8; ++nj) {
            float* base = &G[(size_t)blockIdx.x * 32768 + (size_t)gi0 * 128
                             + (nj << 4) + l15];
#pragma unroll
            for (int r = 0; r < 4; ++r)
                base[r * 128] = 40.f * acc[mi][nj][r];
        }
    }
}

// ----------------------------------------------- persistent barrier ---------
static __device__ __forceinline__ bool bar_arrive(int* cnt, int ph, int t, int* lastf)
{
    __threadfence();
    if (t == 0) *lastf = (atomicAdd(&cnt[ph], 1) == 255);
    __syncthreads();
    return *lastf != 0;
}
static __device__ __forceinline__ void bar_release(int* gen, int ph, int t)
{
    __threadfence();
    if (t == 0) atomicExch(gen, ph);
}
static __device__ __forceinline__ void bar_wait(int* gen, int ph, int t)
{
    if (t == 0) {
        while (atomicCAS(gen, -1, -1) < ph) __builtin_amdgcn_s_sleep(2);
    }
    __syncthreads();
    __threadfence();
}

// ------------------------- persistent Sinkhorn loop + fused finalize --------
// 256 blocks x 256 threads, 1 block/CU. Block b owns G-tile b: rows 0..255 x
// cols [128b, 128b+128), register-resident (float4 tile[32], pinned) for the
// LOOP ONLY. Phase D (R22) reloads G from L3 — tile dead at loop exit, so
// the allocator sees R16's proven pressure profile (no R21 spill).
__global__ __launch_bounds__(256, 1) void sink_loop(
    const float* __restrict__ G, float* __restrict__ su,
    const float* __restrict__ nx, const float* __restrict__ ny,
    float2* __restrict__ pms, float* __restrict__ prow,
    int* __restrict__ cnt, int* __restrict__ gen,
    unsigned* __restrict__ colerr, int* __restrict__ active,
    float* __restrict__ out)
{
    __shared__ float su_lds[256];
    __shared__ float mm[1024];       // [8][128] col partials
    __shared__ float ss[1024];
    __shared__ float Mcol[128];
    __shared__ float Wlds[128];
    __shared__ float ecol[128];
    __shared__ float Rlds[256];
    __shared__ float pq[256 * 33];   // row partials (reused every pass)
    __shared__ float errb[128];
    __shared__ float nxl[256];
    __shared__ float nyl[128];
    __shared__ int lastf;

    const int t  = threadIdx.x;
    const int b  = blockIdx.x;
    const int jq = t & 31;
    const int ig = t >> 5;
    const int c0 = jq << 2;
    const int w  = t >> 6, ln = t & 63;
    const int jy0 = b << 7;
    int ph = 1;

    // ---- load tile (once; live through the loop only) ----
    const float4* G4 = (const float4*)G;
    {
        float4 tile[32];
#pragma unroll
        for (int k = 0; k < 32; ++k) {
            const int i = ig + (k << 3);
            tile[k] = G4[((size_t)b << 13) + (i << 5) + jq];
        }
#pragma unroll
        for (int k = 0; k < 32; ++k) PIN4(tile[k]);

        su_lds[t] = su[t];               // su0 = -20*|x|^2
        __syncthreads();

        // ================= iteration 1 (log-safe, exact lse) =================
        {
            float m0=-INFINITY,m1=-INFINITY,m2=-INFINITY,m3=-INFINITY;
#pragma unroll
            for (int k = 0; k < 32; ++k) {
                const float sk = su_lds[ig + (k << 3)];
                m0=fmaxf(m0,tile[k].x+sk); m1=fmaxf(m1,tile[k].y+sk);
                m2=fmaxf(m2,tile[k].z+sk); m3=fmaxf(m3,tile[k].w+sk);
            }
            float s0=0.f,s1=0.f,s2=0.f,s3=0.f;
#pragma unroll
            for (int k = 0; k < 32; ++k) {
                const float sk = su_lds[ig + (k << 3)];
                s0+=__expf(tile[k].x+sk-m0); s1+=__expf(tile[k].y+sk-m1);
                s2+=__expf(tile[k].z+sk-m2); s3+=__expf(tile[k].w+sk-m3);
            }
            mm[ig*128+c0+0]=m0; ss[ig*128+c0+0]=s0;
            mm[ig*128+c0+1]=m1; ss[ig*128+c0+1]=s1;
            mm[ig*128+c0+2]=m2; ss[ig*128+c0+2]=s2;
            mm[ig*128+c0+3]=m3; ss[ig*128+c0+3]=s3;
            __syncthreads();
            if (t < 128) {
                float m=-INFINITY, s=0.f;
#pragma unroll
                for (int g = 0; g < 8; ++g) {
                    float pmv=mm[g*128+t], psv=ss[g*128+t];
                    float nm=fmaxf(m,pmv);
                    s = s*__expf(m-nm) + psv*__expf(pmv-nm);
                    m = nm;
                }
                Wlds[t] = LOG_B - (m + __logf(s));
            }
            __syncthreads();
        }
        // row pass (exact, two sweeps): rowmax then expsum, cross-block lse
        {
#pragma unroll
            for (int k = 0; k < 32; ++k) {
                const int i = ig + (k << 3);
                float a0=tile[k].x+Wlds[c0], a1=tile[k].y+Wlds[c0+1];
                float a2=tile[k].z+Wlds[c0+2], a3=tile[k].w+Wlds[c0+3];
                pq[i*33+jq] = fmaxf(fmaxf(a0,a1), fmaxf(a2,a3));
            }
            __syncthreads();
            {
                float R=-INFINITY;
#pragma unroll
                for (int qq = 0; qq < 32; ++qq) R = fmaxf(R, pq[t*33+qq]);
                Rlds[t] = R;
            }
            __syncthreads();
#pragma unroll
            for (int k = 0; k < 32; ++k) {
                const int i = ig + (k << 3);
                const float Rr = Rlds[i];
                float s = __expf(tile[k].x+Wlds[c0]-Rr)   + __expf(tile[k].y+Wlds[c0+1]-Rr)
                        + __expf(tile[k].z+Wlds[c0+2]-Rr) + __expf(tile[k].w+Wlds[c0+3]-Rr);
                pq[i*33+jq] = s;
            }
            __syncthreads();
            {
                float s = 0.f;
#pragma unroll
                for (int qq = 0; qq < 32; ++qq) s += pq[t*33+qq];
                pms[(b << 8) + t] = make_float2(Rlds[t], s);
            }
        }
        if (bar_arrive(cnt, ph, t, &lastf)) {
            __threadfence();
            float m=-INFINITY, s=0.f;
            for (int p = 0; p < 256; ++p) {
                float2 v = pms[(p << 8) + t];
                float nm = fmaxf(m, v.x);
                s = s*__expf(m-nm) + v.y*__expf(v.x-nm);
                m = nm;
            }
            su[t] = LOG_A - (m + __logf(s));
            bar_release(gen, ph, t);
        }
        bar_wait(gen, ph, t); ++ph;
        su_lds[t] = su[t];
        __syncthreads();

        // ---- convergence check #1 (ref cpt_n=1): col marginal err vs b ----
        int act;
        {
            float m0=-INFINITY,m1=-INFINITY,m2=-INFINITY,m3=-INFINITY;
#pragma unroll
            for (int k = 0; k < 32; ++k) {
                const float sk = su_lds[ig + (k << 3)];
                m0=fmaxf(m0,tile[k].x+sk); m1=fmaxf(m1,tile[k].y+sk);
                m2=fmaxf(m2,tile[k].z+sk); m3=fmaxf(m3,tile[k].w+sk);
            }
            float s0=0.f,s1=0.f,s2=0.f,s3=0.f;
#pragma unroll
            for (int k = 0; k < 32; ++k) {
                const float sk = su_lds[ig + (k << 3)];
                s0+=__expf(tile[k].x+sk-m0); s1+=__expf(tile[k].y+sk-m1);
                s2+=__expf(tile[k].z+sk-m2); s3+=__expf(tile[k].w+sk-m3);
            }
            mm[ig*128+c0+0]=m0; ss[ig*128+c0+0]=s0;
            mm[ig*128+c0+1]=m1; ss[ig*128+c0+1]=s1;
            mm[ig*128+c0+2]=m2; ss[ig*128+c0+2]=s2;
            mm[ig*128+c0+3]=m3; ss[ig*128+c0+3]=s3;
            __syncthreads();
            if (t < 128) {
                float m=-INFINITY, s=0.f;
#pragma unroll
                for (int g = 0; g < 8; ++g) {
                    float pmv=mm[g*128+t], psv=ss[g*128+t];
                    float nm=fmaxf(m,pmv);
                    s = s*__expf(m-nm) + psv*__expf(pmv-nm);
                    m = nm;
                }
                errb[t] = fabsf(__expf((m + __logf(s)) + Wlds[t]) - BVAL);
            }
            __syncthreads();
            for (int n = 64; n; n >>= 1) {
                if (t < n) errb[t] = fmaxf(errb[t], errb[t + n]);
                __syncthreads();
            }
            if (t == 0) atomicMax(&colerr[0], __float_as_uint(errb[0]));
            if (bar_arrive(cnt, ph, t, &lastf)) {
                if (t == 0) {
                    unsigned e = atomicMax(&colerr[0], 0u);
                    active[0] = (__uint_as_float(e) > 0.005f) ? 1 : 0;
                }
                bar_release(gen, ph, t);
            }
            bar_wait(gen, ph, t); ++ph;
            act = active[0];
        }

        // ================= fast iterations 2..100 (E-reuse) =================
        if (act) {
#pragma unroll 1
            for (int tt = 2; tt <= 100; ++tt) {
                // col pass: true col max, then E = exp(G+su-M), col sums S
                {
                    float m0=-INFINITY,m1=-INFINITY,m2=-INFINITY,m3=-INFINITY;
#pragma unroll
                    for (int k = 0; k < 32; ++k) {
                        const float sk = su_lds[ig + (k << 3)];
                        m0=fmaxf(m0,tile[k].x+sk); m1=fmaxf(m1,tile[k].y+sk);
                        m2=fmaxf(m2,tile[k].z+sk); m3=fmaxf(m3,tile[k].w+sk);
                    }
                    mm[ig*128+c0+0]=m0; mm[ig*128+c0+1]=m1;
                    mm[ig*128+c0+2]=m2; mm[ig*128+c0+3]=m3;
                    __syncthreads();
                    if (t < 128) {
                        float m=-INFINITY;
#pragma unroll
                        for (int g = 0; g < 8; ++g) m = fmaxf(m, mm[g*128+t]);
                        Mcol[t] = m;
                    }
                    __syncthreads();
                }
                float4 E[32];
                {
                    const float Mc0=Mcol[c0], Mc1=Mcol[c0+1], Mc2=Mcol[c0+2], Mc3=Mcol[c0+3];
                    float s0=0.f,s1=0.f,s2=0.f,s3=0.f;
#pragma unroll
                    for (int k = 0; k < 32; ++k) {
                        const float sk = su_lds[ig + (k << 3)];
                        E[k].x=__expf(tile[k].x+sk-Mc0); s0+=E[k].x;
                        E[k].y=__expf(tile[k].y+sk-Mc1); s1+=E[k].y;
                        E[k].z=__expf(tile[k].z+sk-Mc2); s2+=E[k].z;
                        E[k].w=__expf(tile[k].w+sk-Mc3); s3+=E[k].w;
                    }
                    ss[ig*128+c0+0]=s0; ss[ig*128+c0+1]=s1;
                    ss[ig*128+c0+2]=s2; ss[ig*128+c0+3]=s3;
                    __syncthreads();
                    if (t < 128) {
                        float ssum = 0.f;
#pragma unroll
                        for (int g = 0; g < 8; ++g) ssum += ss[g*128+t];
                        Wlds[t] = LOG_B - (Mcol[t] + __logf(ssum));
                        ecol[t] = 1.0f / ssum;
                    }
                    __syncthreads();
                }
                // row pass: partial = dot(E_rowslice, 1/S)
                {
                    const float e0=ecol[c0], e1=ecol[c0+1], e2=ecol[c0+2], e3=ecol[c0+3];
#pragma unroll
                    for (int k = 0; k < 32; ++k) {
                        const int i = ig + (k << 3);
                        pq[i*33+jq] = E[k].x*e0 + E[k].y*e1 + E[k].z*e2 + E[k].w*e3;
                    }
                    __syncthreads();
                    float s = 0.f;
#pragma unroll
                    for (int qq = 0; qq < 32; ++qq) s += pq[t*33+qq];
                    prow[(b << 8) + t] = s;
                }
                if (bar_arrive(cnt, ph, t, &lastf)) {
                    __threadfence();
                    float tot = 0.f;
                    for (int p = 0; p < 256; ++p) tot += prow[(p << 8) + t];
                    su[t] = (LOG_A - LOG_B) + su_lds[t] - __logf(tot);
                    bar_release(gen, ph, t);
                }
                bar_wait(gen, ph, t); ++ph;
                su_lds[t] = su[t];
                __syncthreads();

                if (tt == 51) {
                    // convergence check #2 (ref cpt_n=51)
                    float m0=-INFINITY,m1=-INFINITY,m2=-INFINITY,m3=-INFINITY;
#pragma unroll
                    for (int k = 0; k < 32; ++k) {
                        const float sk = su_lds[ig + (k << 3)];
                        m0=fmaxf(m0,tile[k].x+sk); m1=fmaxf(m1,tile[k].y+sk);
                        m2=fmaxf(m2,tile[k].z+sk); m3=fmaxf(m3,tile[k].w+sk);
                    }
                    float s0=0.f,s1=0.f,s2=0.f,s3=0.f;
#pragma unroll
                    for (int k = 0; k < 32; ++k) {
                        const float sk = su_lds[ig + (k << 3)];
                        s0+=__expf(tile[k].x+sk-m0); s1+=__expf(tile[k].y+sk-m1);
                        s2+=__expf(tile[k].z+sk-m2); s3+=__expf(tile[k].w+sk-m3);
                    }
                    mm[ig*128+c0+0]=m0; ss[ig*128+c0+0]=s0;
                    mm[ig*128+c0+1]=m1; ss[ig*128+c0+1]=s1;
                    mm[ig*128+c0+2]=m2; ss[ig*128+c0+2]=s2;
                    mm[ig*128+c0+3]=m3; ss[ig*128+c0+3]=s3;
                    __syncthreads();
                    if (t < 128) {
                        float m=-INFINITY, s=0.f;
#pragma unroll
                        for (int g = 0; g < 8; ++g) {
                            float pmv=mm[g*128+t], psv=ss[g*128+t];
                            float nm=fmaxf(m,pmv);
                            s = s*__expf(m-nm) + psv*__expf(pmv-nm);
                            m = nm;
                        }
                        errb[t] = fabsf(__expf((m + __logf(s)) + Wlds[t]) - BVAL);
                    }
                    __syncthreads();
                    for (int n = 64; n; n >>= 1) {
                        if (t < n) errb[t] = fmaxf(errb[t], errb[t + n]);
                        __syncthreads();
                    }
                    if (t == 0) atomicMax(&colerr[1], __float_as_uint(errb[0]));
                    if (bar_arrive(cnt, ph, t, &lastf)) {
                        if (t == 0) {
                            unsigned e = atomicMax(&colerr[1], 0u);
                            active[0] = (__uint_as_float(e) > 0.005f) ? 1 : 0;
                        }
                        bar_release(gen, ph, t);
                    }
                    bar_wait(gen, ph, t); ++ph;
                    if (active[0] == 0) break;
                }
            }
        }
    }   // ---- tile dead here (scope closed) ----

    // ================= Phase D: fused finalize (G reloaded from L3) =======
    nxl[t] = nx[t];
    if (t < 128) nyl[t] = ny[jy0 + t];
    __syncthreads();

    const float Wc0 = Wlds[c0+0], Wc1 = Wlds[c0+1], Wc2 = Wlds[c0+2], Wc3 = Wlds[c0+3];
    const float ny0 = nyl[c0+0], ny1 = nyl[c0+1], ny2 = nyl[c0+2], ny3 = nyl[c0+3];
    float accl = 0.f;
#pragma unroll 4
    for (int k = 0; k < 32; ++k) {
        const int i = ig + (k << 3);
        float4 g = G4[((size_t)b << 13) + (i << 5) + jq];   // L3-hot reload
        const float si = su_lds[i], nxi = nxl[i];
        float v0 = __expf(g.x + si + Wc0);
        float v1 = __expf(g.y + si + Wc1);
        float v2 = __expf(g.z + si + Wc2);
        float v3 = __expf(g.w + si + Wc3);
        float* o = out + 1 + (size_t)i * 32768 + jy0 + c0;
        __builtin_nontemporal_store(v0, o + 0);
        __builtin_nontemporal_store(v1, o + 1);
        __builtin_nontemporal_store(v2, o + 2);
        __builtin_nontemporal_store(v3, o + 3);
        accl += v0 * (nxi + ny0 - 0.05f * g.x) +
                v1 * (nxi + ny1 - 0.05f * g.y) +
                v2 * (nxi + ny2 - 0.05f * g.z) +
                v3 * (nxi + ny3 - 0.05f * g.w);
    }
    for (int off = 32; off; off >>= 1) accl += __shfl_down(accl, off);
    if (ln == 0) errb[w] = accl;
    __syncthreads();
    if (t == 0) atomicAdd(out, errb[0] + errb[1] + errb[2] + errb[3]);
}

// ---------------------------------------------------------------- host ------
extern "C" void kernel_launch(void* const* d_in, const int* in_sizes, int n_in,
                              void* d_out, int out_size, void* d_ws, size_t ws_size,
                              hipStream_t stream)
{
    const float* x = (const float*)d_in[0];   // [256, 384]
    const float* y = (const float*)d_in[1];   // [32768, 384]
    float* out = (float*)d_out;               // [1 + 256*32768]

    float* ws   = (float*)d_ws;
    float* G    = ws;                              // 8388608 (tiled [256][256][128])
    float* su   = G + 8388608;                     // 256
    float* nx   = su + 256;                        // 256
    float* ny   = nx + 256;                        // 32768
    float2* pms = (float2*)(ny + 32768);           // 65536 float2
    float* prow = (float*)(pms + 65536);           // 65536
    unsigned* colerr = (unsigned*)(prow + 65536);  // 2
    int* active   = (int*)(colerr + 2);            // 1
    int* counters = active + 1;                    // 4096 (barrier slots + gen)
    int* gen      = counters + 3000;

    init_k<<<8257, 256, 0, stream>>>(x, y, nx, ny, su, colerr, active, counters, out);
    gemm_k<<<dim3(256, 2), 256, 0, stream>>>(x, y, G);
    sink_loop<<<256, 256, 0, stream>>>(G, su, nx, ny, pms, prow,
                                       counters, gen, colerr, active, out);
}